// Round 1
// baseline (392.566 us; speedup 1.0000x reference)
//
#include <hip/hip_runtime.h>
#include <cmath>

// Problem constants
//  x: (32, 2048, 76) f32   conv weights (O,C,5), 1x1 weights (O,C)
//  pipeline: 3x [conv1d(k=5,pad=2) + bias + relu + maxpool2]
//  -> 1x1 conv relu (Wo1,bo1) -> 1x1 conv relu (Wo2,bo2)
//  -> prototype L2 distances, min over 256 positions, log-sim, sigmoid head.
//  out: 32*2 (sigmoid) then 32*128 (min_dis), fp32.

// ---------------------------------------------------------------------------
// Conv + bias + relu + maxpool2 kernel.
// Block: 256 threads. Tile: 64 pre-pool positions (-> 32 pooled) x all 128 oc.
// LDS: input tile [C][68]; weight chunk [128][WROW] (WROW odd => conflict-free).
// Thread blocking: 4 oc x 8 positions (32 accumulators).
// ---------------------------------------------------------------------------
template <int C, int CCHUNK, int Lin, bool CHANNELS_LAST>
__global__ __launch_bounds__(256, 2)
void conv_relu_pool(const float* __restrict__ in, const float* __restrict__ W,
                    const float* __restrict__ bias, float* __restrict__ out)
{
    constexpr int TL   = 64;        // pre-pool positions per block
    constexpr int TIN  = TL + 4;    // 68 (pad 2 each side)
    constexpr int WR5  = CCHUNK * 5;
    constexpr int WROW = (WR5 % 2 == 0) ? WR5 + 1 : WR5;  // odd => dg stride hits distinct banks
    constexpr int NCH  = C / CCHUNK;
    constexpr int Lout = Lin / 2;

    __shared__ float s_in[C * TIN];
    __shared__ float s_w[128 * WROW];

    const int tid  = threadIdx.x;
    const int tile = blockIdx.x;
    const int b    = blockIdx.y;
    const int l0   = tile * TL;

    // ---- load input tile (zero-padded at sequence ends) ----
    if (CHANNELS_LAST) {
        // in[b][l][c]  (the raw x tensor)
        for (int idx = tid; idx < C * TIN; idx += 256) {
            int c = idx % C, pos = idx / C;
            int l = l0 - 2 + pos;
            float v = 0.f;
            if (l >= 0 && l < Lin) v = in[((size_t)b * Lin + l) * C + c];
            s_in[c * TIN + pos] = v;
        }
    } else {
        // in[b][c][l]
        for (int idx = tid; idx < C * TIN; idx += 256) {
            int pos = idx % TIN, c = idx / TIN;
            int l = l0 - 2 + pos;
            float v = 0.f;
            if (l >= 0 && l < Lin) v = in[((size_t)b * C + c) * Lin + l];
            s_in[c * TIN + pos] = v;
        }
    }

    const int dg   = tid >> 3;        // 0..31 -> oc group
    const int ocb  = dg * 4;
    const int posb = (tid & 7) * 8;   // 8 pre-pool positions

    float acc[4][8];
#pragma unroll
    for (int i = 0; i < 4; ++i)
#pragma unroll
        for (int j = 0; j < 8; ++j) acc[i][j] = 0.f;

    for (int ch = 0; ch < NCH; ++ch) {
        __syncthreads();  // input ready / previous chunk compute done
        const int c0 = ch * CCHUNK;
        // stage weight chunk: W[o][c0+cl][k] -> s_w[o][cl*5+k]
        for (int idx = tid; idx < 128 * WR5; idx += 256) {
            int o = idx / WR5, r = idx % WR5;
            s_w[o * WROW + r] = W[((size_t)o * C + c0) * 5 + r];
        }
        __syncthreads();

        for (int cl = 0; cl < CCHUNK; ++cl) {
            const float* irow = &s_in[(c0 + cl) * TIN + posb];
            float xv[12];
#pragma unroll
            for (int j = 0; j < 12; ++j) xv[j] = irow[j];
            const float* wrow = &s_w[cl * 5];
#pragma unroll
            for (int k = 0; k < 5; ++k) {
#pragma unroll
                for (int i = 0; i < 4; ++i) {
                    float w = wrow[(ocb + i) * WROW + k];
#pragma unroll
                    for (int j = 0; j < 8; ++j)
                        acc[i][j] = fmaf(w, xv[k + j], acc[i][j]);
                }
            }
        }
    }

    // ---- bias + relu + maxpool2 + store ----
    const int lpb = (l0 >> 1) + (posb >> 1);
#pragma unroll
    for (int i = 0; i < 4; ++i) {
        float bi = bias[ocb + i];
#pragma unroll
        for (int t = 0; t < 4; ++t) {
            float a0 = fmaxf(acc[i][2 * t]     + bi, 0.f);
            float a1 = fmaxf(acc[i][2 * t + 1] + bi, 0.f);
            out[((size_t)b * 128 + (ocb + i)) * Lout + lpb + t] = fmaxf(a0, a1);
        }
    }
}

// ---------------------------------------------------------------------------
// Head kernel: per (b, 32-position chunk):
//   t1 = relu(Wo1 @ h3 + bo1); t2 = relu(Wo2 @ t1 + bo2)
//   dot[p][pos] = protos . t2 ; dis = sqrt(||t2||^2 + ||p||^2 - 2 dot)
//   partial min over the chunk's 32 positions -> partmin[b][chunk][p]
// K-blocked (32) LDS GEMMs, thread blocking 4 out x 4 pos.
// ---------------------------------------------------------------------------
__device__ __forceinline__ void mm_block(const float* __restrict__ G,  // 128x128 row-major
                                         const float* sIn,            // [128][32]
                                         float* sWblk,                 // [128][33]
                                         float acc[4][4], int db, int jb, int tid)
{
#pragma unroll
    for (int i = 0; i < 4; ++i)
#pragma unroll
        for (int j = 0; j < 4; ++j) acc[i][j] = 0.f;

    for (int cb = 0; cb < 128; cb += 32) {
        __syncthreads();  // previous users of sWblk / producers of sIn done
        for (int idx = tid; idx < 128 * 32; idx += 256) {
            int d = idx >> 5, c = idx & 31;
            sWblk[d * 33 + c] = G[d * 128 + cb + c];
        }
        __syncthreads();
#pragma unroll
        for (int c = 0; c < 32; ++c) {
            float av[4];
#pragma unroll
            for (int j = 0; j < 4; ++j) av[j] = sIn[(cb + c) * 32 + jb + j];
#pragma unroll
            for (int i = 0; i < 4; ++i) {
                float w = sWblk[(db + i) * 33 + c];
#pragma unroll
                for (int j = 0; j < 4; ++j) acc[i][j] = fmaf(w, av[j], acc[i][j]);
            }
        }
    }
}

__global__ __launch_bounds__(256)
void head_kernel(const float* __restrict__ h3,   // (32,128,256)
                 const float* __restrict__ Wo1, const float* __restrict__ bo1,
                 const float* __restrict__ Wo2, const float* __restrict__ bo2,
                 const float* __restrict__ protos,  // (128,128)
                 float* __restrict__ partmin)       // (32,8,128)
{
    constexpr int TP = 32;
    __shared__ float sA[128 * TP];
    __shared__ float sB[128 * TP];
    __shared__ float sWblk[128 * 33];
    __shared__ float s_fn[TP];
    __shared__ float s_pn[128];
    __shared__ float s_min[8 * 128];

    const int tid   = threadIdx.x;
    const int chunk = blockIdx.x;   // 0..7
    const int b     = blockIdx.y;   // 0..31
    const int p0    = chunk * TP;

    const int dg = tid >> 3;
    const int db = dg * 4;
    const int jb = (tid & 7) * 4;

    // load h3 chunk -> sA  [c][pos]
    for (int idx = tid; idx < 128 * TP; idx += 256) {
        int c = idx >> 5, j = idx & 31;
        sA[c * TP + j] = h3[((size_t)b * 128 + c) * 256 + p0 + j];
    }

    float acc[4][4];

    // t1 = relu(Wo1 @ h3 + bo1) -> sB
    mm_block(Wo1, sA, sWblk, acc, db, jb, tid);
#pragma unroll
    for (int i = 0; i < 4; ++i) {
        float bi = bo1[db + i];
#pragma unroll
        for (int j = 0; j < 4; ++j)
            sB[(db + i) * TP + jb + j] = fmaxf(acc[i][j] + bi, 0.f);
    }

    // t2 = relu(Wo2 @ t1 + bo2) -> sA
    mm_block(Wo2, sB, sWblk, acc, db, jb, tid);
#pragma unroll
    for (int i = 0; i < 4; ++i) {
        float bi = bo2[db + i];
#pragma unroll
        for (int j = 0; j < 4; ++j)
            sA[(db + i) * TP + jb + j] = fmaxf(acc[i][j] + bi, 0.f);
    }
    __syncthreads();

    // ||p||^2 (from global, L1-hot) and ||f||^2 (from sA)
    if (tid < 128) {
        float s = 0.f;
        for (int d = 0; d < 128; ++d) {
            float v = protos[tid * 128 + d];
            s = fmaf(v, v, s);
        }
        s_pn[tid] = s;
    } else if (tid < 128 + TP) {
        int j = tid - 128;
        float s = 0.f;
        for (int d = 0; d < 128; ++d) {
            float v = sA[d * TP + j];
            s = fmaf(v, v, s);
        }
        s_fn[j] = s;
    }
    // dot[p][pos] = protos @ t2   (mm_block's internal syncs order s_pn/s_fn too)
    mm_block(protos, sA, sWblk, acc, db, jb, tid);

#pragma unroll
    for (int i = 0; i < 4; ++i) {
        float pn = s_pn[db + i];
        float m = 3.0e38f;
#pragma unroll
        for (int j = 0; j < 4; ++j) {
            float d2  = s_fn[jb + j] + pn - 2.f * acc[i][j];
            float dis = sqrtf(fmaxf(d2, 1e-12f));
            m = fminf(m, dis);
        }
        s_min[(tid & 7) * 128 + db + i] = m;
    }
    __syncthreads();
    if (tid < 128) {
        float m = s_min[tid];
#pragma unroll
        for (int g = 1; g < 8; ++g) m = fminf(m, s_min[g * 128 + tid]);
        partmin[((size_t)b * 8 + chunk) * 128 + tid] = m;
    }
}

// ---------------------------------------------------------------------------
// Finalize: min over chunks, write min_dis, log-sim, class head, sigmoid.
// ---------------------------------------------------------------------------
__global__ __launch_bounds__(128)
void finalize_kernel(const float* __restrict__ partmin,  // (32,8,128)
                     const int* __restrict__ classes,    // (128,)
                     float* __restrict__ out)            // [64 sigmoid][4096 min_dis]
{
    __shared__ float r0[128], r1[128];
    const int b = blockIdx.x, p = threadIdx.x;
    float m = partmin[((size_t)b * 8) * 128 + p];
#pragma unroll
    for (int q = 1; q < 8; ++q)
        m = fminf(m, partmin[((size_t)b * 8 + q) * 128 + p]);
    out[64 + b * 128 + p] = m;

    float sim = logf((m + 1.0f) / (m + 1e-4f));
    int cls = classes[p];
    r0[p] = (cls == 0) ? sim : -0.5f * sim;
    r1[p] = (cls == 1) ? sim : -0.5f * sim;
    __syncthreads();
    for (int s = 64; s > 0; s >>= 1) {
        if (p < s) { r0[p] += r0[p + s]; r1[p] += r1[p + s]; }
        __syncthreads();
    }
    if (p == 0) {
        out[b * 2 + 0] = 1.f / (1.f + expf(-r0[0]));
        out[b * 2 + 1] = 1.f / (1.f + expf(-r1[0]));
    }
}

// ---------------------------------------------------------------------------
extern "C" void kernel_launch(void* const* d_in, const int* in_sizes, int n_in,
                              void* d_out, int out_size, void* d_ws, size_t ws_size,
                              hipStream_t stream)
{
    (void)in_sizes; (void)n_in; (void)out_size; (void)ws_size;
    const float* x    = (const float*)d_in[0];
    const float* W1   = (const float*)d_in[1];
    const float* b1   = (const float*)d_in[2];
    const float* W2   = (const float*)d_in[3];
    const float* b2   = (const float*)d_in[4];
    const float* W3   = (const float*)d_in[5];
    const float* b3   = (const float*)d_in[6];
    const float* Wo1  = (const float*)d_in[7];
    const float* bo1  = (const float*)d_in[8];
    const float* Wo2  = (const float*)d_in[9];
    const float* bo2  = (const float*)d_in[10];
    const float* prot = (const float*)d_in[11];
    const int*   cls  = (const int*)d_in[12];
    float* out = (float*)d_out;

    // workspace layout (fp32): h1 (32,128,1024) | h2 (32,128,512) | partmin (32,8,128)
    float* h1      = (float*)d_ws;
    float* h2      = h1 + (size_t)32 * 128 * 1024;
    float* h3      = h1;  // reuse: h1 dead once conv3 runs
    float* partmin = h2 + (size_t)32 * 128 * 512;

    conv_relu_pool< 76, 4, 2048, true ><<<dim3(32, 32), 256, 0, stream>>>(x,  W1, b1, h1);
    conv_relu_pool<128, 8, 1024, false><<<dim3(16, 32), 256, 0, stream>>>(h1, W2, b2, h2);
    conv_relu_pool<128, 8,  512, false><<<dim3( 8, 32), 256, 0, stream>>>(h2, W3, b3, h3);
    head_kernel<<<dim3(8, 32), 256, 0, stream>>>(h3, Wo1, bo1, Wo2, bo2, prot, partmin);
    finalize_kernel<<<32, 128, 0, stream>>>(partmin, cls, out);
}

// Round 2
// 154.965 us; speedup vs baseline: 2.5333x; 2.5333x over previous
//
#include <hip/hip_runtime.h>
#include <cmath>

// ProtICU on MI355X — bf16 MFMA implicit-GEMM pipeline.
//  x (32,2048,76) f32 -> bf16 pad96 -> 3x [conv k=5 as 5 tap-GEMMs + bias+relu+pool2]
//  -> head: two 1x1 GEMMs + prototype-distance GEMM, min over 256 positions
//  -> finalize: log-sim, class head, sigmoid.
// All GEMMs: v_mfma_f32_16x16x32_bf16, fp32 accumulate.
// A-fragments pre-packed in ws by prep kernel (lane-exact layout, global dwordx4 loads).
// B-fragments from LDS tiles [pos][Cpad+8] (row stride 52/68 dwords -> <=2-way bank alias, free).

typedef __attribute__((ext_vector_type(8))) short short8;
typedef __attribute__((ext_vector_type(4))) float f32x4;

__device__ __forceinline__ unsigned short f2bf(float v) {
    union { float f; unsigned u; } x; x.f = v;
    unsigned r = x.u + 0x7fffu + ((x.u >> 16) & 1u);   // RNE
    return (unsigned short)(r >> 16);
}
__device__ __forceinline__ float bf2f(unsigned short b) {
    union { unsigned u; float f; } x; x.u = ((unsigned)b) << 16;
    return x.f;
}

// ---------------------------------------------------------------------------
// Convert x (32,2048,76) f32 channels-last -> bf16 padded to 96 channels.
// ---------------------------------------------------------------------------
__global__ __launch_bounds__(256)
void convert_x_kernel(const float* __restrict__ x, unsigned short* __restrict__ xb)
{
    int t = blockIdx.x * 256 + threadIdx.x;      // exactly 32*2048*12 threads
    int row = t / 12, c0 = (t % 12) * 8;
    unsigned short v[8];
#pragma unroll
    for (int j = 0; j < 8; ++j) {
        int c = c0 + j;
        v[j] = (c < 76) ? f2bf(x[(size_t)row * 76 + c]) : (unsigned short)0;
    }
    *(uint4*)&xb[(size_t)row * 96 + c0] = *(uint4*)v;
}

// ---------------------------------------------------------------------------
// Weight packing into MFMA A-fragment order.
// A-frag (16x16x32): lane holds A[m = mf*16 + (lane&15)][k = cc*32 + (lane>>4)*8 + j]
// conv: dst[((cc*5+kk)*8+mf)*64+lane][8] = W[m][c][kk]   (c >= C -> 0)
// mat : dst[((cc  )*8+mf)*64+lane][8] = M[m][c]
// ---------------------------------------------------------------------------
__device__ void pack_conv_w(int t, int total, const float* __restrict__ W, int C,
                            unsigned short* __restrict__ dst)
{
    if (t >= total) return;
    int lane = t & 63, rest = t >> 6;
    int mf = rest & 7; rest >>= 3;
    int kk = rest % 5, cc = rest / 5;
    int m = mf * 16 + (lane & 15);
    int cb = cc * 32 + (lane >> 4) * 8;
    unsigned short v[8];
#pragma unroll
    for (int j = 0; j < 8; ++j) {
        int c = cb + j;
        v[j] = (c < C) ? f2bf(W[((size_t)m * C + c) * 5 + kk]) : (unsigned short)0;
    }
    *(uint4*)&dst[(size_t)t * 8] = *(uint4*)v;
}

__device__ void pack_mat(int t, const float* __restrict__ M, unsigned short* __restrict__ dst)
{
    if (t >= 2048) return;
    int lane = t & 63, mf = (t >> 6) & 7, cc = t >> 9;
    int m = mf * 16 + (lane & 15);
    int c0 = cc * 32 + (lane >> 4) * 8;
    unsigned short v[8];
#pragma unroll
    for (int j = 0; j < 8; ++j) v[j] = f2bf(M[(size_t)m * 128 + c0 + j]);
    *(uint4*)&dst[(size_t)t * 8] = *(uint4*)v;
}

__global__ __launch_bounds__(256)
void prep_weights_kernel(const float* __restrict__ W1, const float* __restrict__ W2,
                         const float* __restrict__ W3, const float* __restrict__ Wo1,
                         const float* __restrict__ Wo2, const float* __restrict__ protos,
                         unsigned short* A1, unsigned short* A2, unsigned short* A3,
                         unsigned short* AW1, unsigned short* AW2, unsigned short* AP,
                         float* pn)
{
    int t = blockIdx.x * 256 + threadIdx.x;
    switch (blockIdx.y) {
    case 0: pack_conv_w(t, 7680,  W1, 76,  A1); break;
    case 1: pack_conv_w(t, 10240, W2, 128, A2); break;
    case 2: pack_conv_w(t, 10240, W3, 128, A3); break;
    case 3: pack_mat(t, Wo1, AW1); break;
    case 4: pack_mat(t, Wo2, AW2); break;
    case 5: pack_mat(t, protos, AP); break;
    case 6:
        if (t < 128) {
            float s = 0.f;
            for (int d = 0; d < 128; ++d) {
                float v = bf2f(f2bf(protos[(size_t)t * 128 + d]));
                s = fmaf(v, v, s);
            }
            pn[t] = s;
        }
        break;
    }
}

// ---------------------------------------------------------------------------
// Conv (k=5, pad=2) + bias + relu + maxpool2 as MFMA implicit GEMM.
// Block = 256 thr = 4 waves. Tile: M=128 oc x N=64 pre-pool pos (-> 32 pooled).
// Wave tile 64x32: mf in [mh,mh+4), n in [nh,nh+32). K-loop: NCH chunks x 5 taps.
// in/out: bf16 channels-last [b][l][CPAD_G] / [b][l/2][128].
// ---------------------------------------------------------------------------
template <int CPAD_G, int LIN>
__global__ __launch_bounds__(256)
void conv_mfma(const unsigned short* __restrict__ in, const unsigned short* __restrict__ Af,
               const float* __restrict__ bias, unsigned short* __restrict__ out)
{
    constexpr int NCH    = CPAD_G / 32;
    constexpr int CPAD_L = CPAD_G + 8;      // +16B pad: row stride 52/68 dwords
    constexpr int LOUT   = LIN / 2;
    constexpr int CW     = CPAD_G / 8;

    __shared__ __align__(16) unsigned short s_in[68 * CPAD_L];
    __shared__ float s_bias[128];

    const int tid = threadIdx.x;
    const int b   = blockIdx.y;
    const int l0  = blockIdx.x * 64;

    if (tid < 128) s_bias[tid] = bias[tid];

    for (int idx = tid; idx < 68 * CW; idx += 256) {
        int pos = idx / CW, co = (idx % CW) * 8;
        int l = l0 - 2 + pos;
        uint4 v = make_uint4(0u, 0u, 0u, 0u);
        if (l >= 0 && l < LIN)
            v = *(const uint4*)&in[((size_t)b * LIN + l) * CPAD_G + co];
        *(uint4*)&s_in[pos * CPAD_L + co] = v;
    }
    __syncthreads();

    const int lane = tid & 63;
    const int wid  = tid >> 6;
    const int mh   = (wid & 1) * 4;     // m-frag base (x16 oc)
    const int nh   = (wid >> 1) * 32;   // n base
    const int lc   = lane & 15;
    const int lk   = (lane >> 4) * 8;

    const f32x4 zero = {0.f, 0.f, 0.f, 0.f};
    f32x4 acc[4][2];
#pragma unroll
    for (int i = 0; i < 4; ++i)
#pragma unroll
        for (int j = 0; j < 2; ++j) acc[i][j] = zero;

    for (int cc = 0; cc < NCH; ++cc) {
#pragma unroll
        for (int kk = 0; kk < 5; ++kk) {
            const int step = cc * 5 + kk;
            short8 a[4];
#pragma unroll
            for (int i = 0; i < 4; ++i)
                a[i] = *(const short8*)&Af[(((size_t)step * 8 + mh + i) * 64 + lane) * 8];
            short8 bb[2];
#pragma unroll
            for (int j = 0; j < 2; ++j) {
                int row = nh + j * 16 + lc + kk;
                bb[j] = *(const short8*)&s_in[row * CPAD_L + cc * 32 + lk];
            }
#pragma unroll
            for (int i = 0; i < 4; ++i)
#pragma unroll
                for (int j = 0; j < 2; ++j)
                    acc[i][j] = __builtin_amdgcn_mfma_f32_16x16x32_bf16(a[i], bb[j], acc[i][j], 0, 0, 0);
        }
    }

    // bias + relu + pool2 (shfl pair-max) + bf16 store channels-last
    const int lp0 = l0 >> 1;
#pragma unroll
    for (int i = 0; i < 4; ++i) {
        const int ch0 = (mh + i) * 16 + (lane >> 4) * 4;
#pragma unroll
        for (int j = 0; j < 2; ++j) {
            const int n = nh + j * 16 + lc;
            unsigned short pk[4];
#pragma unroll
            for (int r = 0; r < 4; ++r) {
                float v = fmaxf(acc[i][j][r] + s_bias[ch0 + r], 0.f);
                float o = __shfl_xor(v, 1);
                pk[r] = f2bf(fmaxf(v, o));
            }
            if ((lc & 1) == 0)
                *(uint2*)&out[((size_t)b * LOUT + lp0 + (n >> 1)) * 128 + ch0] = *(uint2*)pk;
        }
    }
}

// ---------------------------------------------------------------------------
// Head: per (b, 64-pos chunk): t1=relu(Wo1@f+b1); t2=relu(Wo2@t1+b2);
// dot=P@t2; dis=sqrt(fn+pn-2dot); partial min over 64 positions.
// ---------------------------------------------------------------------------
__global__ __launch_bounds__(256)
void head_mfma(const unsigned short* __restrict__ f,     // (32,256,128) bf16
               const unsigned short* __restrict__ AW1, const float* __restrict__ bo1,
               const unsigned short* __restrict__ AW2, const float* __restrict__ bo2,
               const unsigned short* __restrict__ AP,  const float* __restrict__ pn,
               float* __restrict__ partmin)              // (32,4,128)
{
    constexpr int CP = 136;
    __shared__ __align__(16) unsigned short s_f[64 * CP];
    __shared__ float s_fn[64];
    __shared__ float s_part[4 * 64];
    __shared__ float s_min[2 * 128];

    const int tid = threadIdx.x;
    const int b   = blockIdx.y;
    const int p0  = blockIdx.x * 64;

    for (int idx = tid; idx < 64 * 16; idx += 256) {
        int pos = idx >> 4, co = (idx & 15) * 8;
        *(uint4*)&s_f[pos * CP + co] =
            *(const uint4*)&f[((size_t)b * 256 + p0 + pos) * 128 + co];
    }
    __syncthreads();

    const int lane = tid & 63;
    const int wid  = tid >> 6;
    const int mh   = (wid & 1) * 4;
    const int nh   = (wid >> 1) * 32;
    const int lc   = lane & 15;
    const int lk   = (lane >> 4) * 8;

    const f32x4 zero = {0.f, 0.f, 0.f, 0.f};
    f32x4 acc[4][2];

    auto gemm = [&](const unsigned short* __restrict__ A) {
#pragma unroll
        for (int i = 0; i < 4; ++i)
#pragma unroll
            for (int j = 0; j < 2; ++j) acc[i][j] = zero;
        for (int cc = 0; cc < 4; ++cc) {
            short8 a[4];
#pragma unroll
            for (int i = 0; i < 4; ++i)
                a[i] = *(const short8*)&A[(((size_t)cc * 8 + mh + i) * 64 + lane) * 8];
            short8 bb[2];
#pragma unroll
            for (int j = 0; j < 2; ++j)
                bb[j] = *(const short8*)&s_f[(nh + j * 16 + lc) * CP + cc * 32 + lk];
#pragma unroll
            for (int i = 0; i < 4; ++i)
#pragma unroll
                for (int j = 0; j < 2; ++j)
                    acc[i][j] = __builtin_amdgcn_mfma_f32_16x16x32_bf16(a[i], bb[j], acc[i][j], 0, 0, 0);
        }
    };

    auto store_relu = [&](const float* __restrict__ bias) {
        __syncthreads();   // all reads of s_f done
#pragma unroll
        for (int i = 0; i < 4; ++i) {
            const int ch0 = (mh + i) * 16 + (lane >> 4) * 4;
#pragma unroll
            for (int j = 0; j < 2; ++j) {
                const int n = nh + j * 16 + lc;
                unsigned short pk[4];
#pragma unroll
                for (int r = 0; r < 4; ++r)
                    pk[r] = f2bf(fmaxf(acc[i][j][r] + bias[ch0 + r], 0.f));
                *(uint2*)&s_f[n * CP + ch0] = *(uint2*)pk;
            }
        }
        __syncthreads();
    };

    gemm(AW1); store_relu(bo1);
    gemm(AW2); store_relu(bo2);

    // fn[n] = ||t2[n]||^2  (partials over 4 channel-quarters)
    {
        int n = tid >> 2, part = tid & 3;
        float s = 0.f;
        for (int c = part * 32; c < part * 32 + 32; ++c) {
            float v = bf2f(s_f[n * CP + c]);
            s = fmaf(v, v, s);
        }
        s_part[part * 64 + n] = s;
    }
    __syncthreads();
    if (tid < 64)
        s_fn[tid] = s_part[tid] + s_part[64 + tid] + s_part[128 + tid] + s_part[192 + tid];
    __syncthreads();

    gemm(AP);

    // dis + min over this block's 64 positions
#pragma unroll
    for (int i = 0; i < 4; ++i) {
#pragma unroll
        for (int r = 0; r < 4; ++r) {
            const int p = (mh + i) * 16 + (lane >> 4) * 4 + r;
            float m = 3.0e38f;
#pragma unroll
            for (int j = 0; j < 2; ++j) {
                const int n = nh + j * 16 + lc;
                float d2 = s_fn[n] + pn[p] - 2.f * acc[i][j][r];
                m = fminf(m, sqrtf(fmaxf(d2, 1e-12f)));
            }
#pragma unroll
            for (int s = 1; s < 16; s <<= 1)
                m = fminf(m, __shfl_xor(m, s));
            if (lc == 0) s_min[(wid >> 1) * 128 + p] = m;
        }
    }
    __syncthreads();
    if (tid < 128)
        partmin[((size_t)b * 4 + blockIdx.x) * 128 + tid] = fminf(s_min[tid], s_min[128 + tid]);
}

// ---------------------------------------------------------------------------
__global__ __launch_bounds__(128)
void finalize_kernel(const float* __restrict__ partmin,  // (32,4,128)
                     const int* __restrict__ classes,
                     float* __restrict__ out)            // [64 sigmoid][4096 min_dis]
{
    __shared__ float r0[128], r1[128];
    const int b = blockIdx.x, p = threadIdx.x;
    float m = partmin[((size_t)b * 4) * 128 + p];
#pragma unroll
    for (int q = 1; q < 4; ++q)
        m = fminf(m, partmin[((size_t)b * 4 + q) * 128 + p]);
    out[64 + b * 128 + p] = m;

    float sim = logf((m + 1.0f) / (m + 1e-4f));
    int cls = classes[p];
    r0[p] = (cls == 0) ? sim : -0.5f * sim;
    r1[p] = (cls == 1) ? sim : -0.5f * sim;
    __syncthreads();
    for (int s = 64; s > 0; s >>= 1) {
        if (p < s) { r0[p] += r0[p + s]; r1[p] += r1[p + s]; }
        __syncthreads();
    }
    if (p == 0) {
        out[b * 2 + 0] = 1.f / (1.f + expf(-r0[0]));
        out[b * 2 + 1] = 1.f / (1.f + expf(-r1[0]));
    }
}

// ---------------------------------------------------------------------------
extern "C" void kernel_launch(void* const* d_in, const int* in_sizes, int n_in,
                              void* d_out, int out_size, void* d_ws, size_t ws_size,
                              hipStream_t stream)
{
    (void)in_sizes; (void)n_in; (void)out_size; (void)ws_size;
    const float* x    = (const float*)d_in[0];
    const float* W1   = (const float*)d_in[1];
    const float* b1   = (const float*)d_in[2];
    const float* W2   = (const float*)d_in[3];
    const float* b2   = (const float*)d_in[4];
    const float* W3   = (const float*)d_in[5];
    const float* b3   = (const float*)d_in[6];
    const float* Wo1  = (const float*)d_in[7];
    const float* bo1  = (const float*)d_in[8];
    const float* Wo2  = (const float*)d_in[9];
    const float* bo2  = (const float*)d_in[10];
    const float* prot = (const float*)d_in[11];
    const int*   cls  = (const int*)d_in[12];
    float* out = (float*)d_out;

    // ws layout (bytes), peak ~21.6 MB (<= 25.3 MB proven available in R1):
    //  xb @0 (12.58M) | h1 @12.58M (8.39M)   -- concurrent during conv1
    //  h2 @0 (4.19M, xb dead) | h3 @4.19M (2.10M, h1 dead) | frags @20.97M
    char* ws = (char*)d_ws;
    unsigned short* xb = (unsigned short*)(ws);
    unsigned short* h1 = (unsigned short*)(ws + 12582912);
    unsigned short* h2 = (unsigned short*)(ws);
    unsigned short* h3 = (unsigned short*)(ws + 4194304);
    const size_t FR = 20971520;
    unsigned short* A1  = (unsigned short*)(ws + FR);
    unsigned short* A2  = (unsigned short*)(ws + FR + 122880);
    unsigned short* A3  = (unsigned short*)(ws + FR + 286720);
    unsigned short* AW1 = (unsigned short*)(ws + FR + 450560);
    unsigned short* AW2 = (unsigned short*)(ws + FR + 483328);
    unsigned short* AP  = (unsigned short*)(ws + FR + 516096);
    float*          pn  = (float*)(ws + FR + 548864);
    float*          pm  = (float*)(ws + FR + 549376);

    convert_x_kernel<<<3072, 256, 0, stream>>>(x, xb);
    prep_weights_kernel<<<dim3(40, 7), 256, 0, stream>>>(W1, W2, W3, Wo1, Wo2, prot,
                                                         A1, A2, A3, AW1, AW2, AP, pn);
    conv_mfma< 96, 2048><<<dim3(32, 32), 256, 0, stream>>>(xb, A1, b1, h1);
    conv_mfma<128, 1024><<<dim3(16, 32), 256, 0, stream>>>(h1, A2, b2, h2);
    conv_mfma<128,  512><<<dim3( 8, 32), 256, 0, stream>>>(h2, A3, b3, h3);
    head_mfma<<<dim3(4, 32), 256, 0, stream>>>(h3, AW1, bo1, AW2, bo2, AP, pn, pm);
    finalize_kernel<<<32, 128, 0, stream>>>(pm, cls, out);
}

// Round 3
// 133.137 us; speedup vs baseline: 2.9486x; 1.1640x over previous
//
#include <hip/hip_runtime.h>
#include <cmath>

// ProtICU on MI355X — bf16 MFMA implicit-GEMM pipeline, round 3.
//  conv1 (fused f32->bf16 convert) -> conv2 -> conv3+head (fused, atomicMin) -> finalize
//  All GEMMs: v_mfma_f32_16x16x32_bf16, fp32 accumulate.
//  Wave tile = 32oc x 64pos (acc[2][4]): 4 waves/block cover disjoint m-frags
//  -> no duplicated A-fragment loads within a block (halves L2 A-traffic vs R2).
//  A-fragments pre-packed lane-exact in ws; B from LDS rows [pos][Cpad+8]
//  (row stride 52/68 dwords -> <=2-way bank alias, free per m136).

typedef __attribute__((ext_vector_type(8))) short short8;
typedef __attribute__((ext_vector_type(4))) float f32x4;

__device__ __forceinline__ unsigned short f2bf(float v) {
    union { float f; unsigned u; } x; x.f = v;
    unsigned r = x.u + 0x7fffu + ((x.u >> 16) & 1u);   // RNE
    return (unsigned short)(r >> 16);
}
__device__ __forceinline__ float bf2f(unsigned short b) {
    union { unsigned u; float f; } x; x.u = ((unsigned)b) << 16;
    return x.f;
}

// ---------------------------------------------------------------------------
// Weight packing into MFMA A-fragment order.
// A-frag (16x16x32): lane holds A[m = mf*16 + (lane&15)][k = cc*32 + (lane>>4)*8 + j]
// conv: dst[((cc*5+kk)*8+mf)*64+lane][8] = W[m][c][kk]   (c >= C -> 0)
// mat : dst[((cc  )*8+mf)*64+lane][8] = M[m][c]
// ---------------------------------------------------------------------------
__device__ void pack_conv_w(int t, int total, const float* __restrict__ W, int C,
                            unsigned short* __restrict__ dst)
{
    if (t >= total) return;
    int lane = t & 63, rest = t >> 6;
    int mf = rest & 7; rest >>= 3;
    int kk = rest % 5, cc = rest / 5;
    int m = mf * 16 + (lane & 15);
    int cb = cc * 32 + (lane >> 4) * 8;
    unsigned short v[8];
#pragma unroll
    for (int j = 0; j < 8; ++j) {
        int c = cb + j;
        v[j] = (c < C) ? f2bf(W[((size_t)m * C + c) * 5 + kk]) : (unsigned short)0;
    }
    *(uint4*)&dst[(size_t)t * 8] = *(uint4*)v;
}

__device__ void pack_mat(int t, const float* __restrict__ M, unsigned short* __restrict__ dst)
{
    if (t >= 2048) return;
    int lane = t & 63, mf = (t >> 6) & 7, cc = t >> 9;
    int m = mf * 16 + (lane & 15);
    int c0 = cc * 32 + (lane >> 4) * 8;
    unsigned short v[8];
#pragma unroll
    for (int j = 0; j < 8; ++j) v[j] = f2bf(M[(size_t)m * 128 + c0 + j]);
    *(uint4*)&dst[(size_t)t * 8] = *(uint4*)v;
}

__global__ __launch_bounds__(256)
void prep_weights_kernel(const float* __restrict__ W1, const float* __restrict__ W2,
                         const float* __restrict__ W3, const float* __restrict__ Wo1,
                         const float* __restrict__ Wo2, const float* __restrict__ protos,
                         unsigned short* A1, unsigned short* A2, unsigned short* A3,
                         unsigned short* AW1, unsigned short* AW2, unsigned short* AP,
                         float* pn, unsigned* pm_bits)
{
    int t = blockIdx.x * 256 + threadIdx.x;
    switch (blockIdx.y) {
    case 0: pack_conv_w(t, 7680,  W1, 76,  A1); break;
    case 1: pack_conv_w(t, 10240, W2, 128, A2); break;
    case 2: pack_conv_w(t, 10240, W3, 128, A3); break;
    case 3: pack_mat(t, Wo1, AW1); break;
    case 4: pack_mat(t, Wo2, AW2); break;
    case 5: pack_mat(t, protos, AP); break;
    case 6:
        if (t < 128) {
            float s = 0.f;
            for (int d = 0; d < 128; ++d) {
                float v = bf2f(f2bf(protos[(size_t)t * 128 + d]));
                s = fmaf(v, v, s);
            }
            pn[t] = s;
        }
        break;
    case 7:
        if (t < 4096) pm_bits[t] = 0x7F800000u;   // +inf init for atomicMin
        break;
    }
}

// ---------------------------------------------------------------------------
// conv1: x f32 (32,2048,76) channels-last -> fused bf16 convert in staging.
// Tile: M=128 oc x N=64 pre-pool (-> 32 pooled). Wave: 32oc x 64pos, acc[2][4].
// ---------------------------------------------------------------------------
__global__ __launch_bounds__(256)
void conv1_mfma(const float* __restrict__ x, const unsigned short* __restrict__ Af,
                const float* __restrict__ bias, unsigned short* __restrict__ out)
{
    constexpr int LIN = 2048, LOUT = 1024, CPL = 104;   // 96 + 8 pad
    __shared__ __align__(16) unsigned short s_in[68 * CPL];
    __shared__ float s_bias[128];

    const int tid = threadIdx.x;
    const int b   = blockIdx.y;
    const int l0  = blockIdx.x * 64;

    if (tid < 128) s_bias[tid] = bias[tid];

    for (int idx = tid; idx < 68 * 24; idx += 256) {
        int pos = idx / 24, c0 = (idx % 24) * 4;
        int l = l0 - 2 + pos;
        unsigned short v[4] = {0, 0, 0, 0};
        if (c0 < 76 && l >= 0 && l < LIN) {
            float4 xv = *(const float4*)&x[((size_t)b * LIN + l) * 76 + c0];
            v[0] = f2bf(xv.x); v[1] = f2bf(xv.y); v[2] = f2bf(xv.z); v[3] = f2bf(xv.w);
        }
        *(uint2*)&s_in[pos * CPL + c0] = *(uint2*)v;
    }
    __syncthreads();

    const int lane = tid & 63;
    const int mf0  = (tid >> 6) * 2;    // wave's 2 m-frags (disjoint across waves)
    const int lc   = lane & 15;
    const int lk   = (lane >> 4) * 8;

    const f32x4 zero = {0.f, 0.f, 0.f, 0.f};
    f32x4 acc[2][4];
#pragma unroll
    for (int i = 0; i < 2; ++i)
#pragma unroll
        for (int j = 0; j < 4; ++j) acc[i][j] = zero;

    for (int cc = 0; cc < 3; ++cc) {
#pragma unroll
        for (int kk = 0; kk < 5; ++kk) {
            const int step = cc * 5 + kk;
            short8 a[2];
#pragma unroll
            for (int i = 0; i < 2; ++i)
                a[i] = *(const short8*)&Af[(((size_t)step * 8 + mf0 + i) * 64 + lane) * 8];
            short8 bb[4];
#pragma unroll
            for (int j = 0; j < 4; ++j)
                bb[j] = *(const short8*)&s_in[(j * 16 + lc + kk) * CPL + cc * 32 + lk];
#pragma unroll
            for (int i = 0; i < 2; ++i)
#pragma unroll
                for (int j = 0; j < 4; ++j)
                    acc[i][j] = __builtin_amdgcn_mfma_f32_16x16x32_bf16(a[i], bb[j], acc[i][j], 0, 0, 0);
        }
    }

    const int lp0 = l0 >> 1;
#pragma unroll
    for (int i = 0; i < 2; ++i) {
        const int ch0 = (mf0 + i) * 16 + (lane >> 4) * 4;
#pragma unroll
        for (int j = 0; j < 4; ++j) {
            const int n = j * 16 + lc;
            unsigned short pk[4];
#pragma unroll
            for (int r = 0; r < 4; ++r) {
                float v = fmaxf(acc[i][j][r] + s_bias[ch0 + r], 0.f);
                float o = __shfl_xor(v, 1);
                pk[r] = f2bf(fmaxf(v, o));
            }
            if ((lc & 1) == 0)
                *(uint2*)&out[((size_t)b * LOUT + lp0 + (n >> 1)) * 128 + ch0] = *(uint2*)pk;
        }
    }
}

// ---------------------------------------------------------------------------
// conv2: bf16 (32,1024,128) -> (32,512,128). Same wave tiling.
// ---------------------------------------------------------------------------
__global__ __launch_bounds__(256)
void conv2_mfma(const unsigned short* __restrict__ in, const unsigned short* __restrict__ Af,
                const float* __restrict__ bias, unsigned short* __restrict__ out)
{
    constexpr int LIN = 1024, LOUT = 512, CPL = 136;
    __shared__ __align__(16) unsigned short s_in[68 * CPL];
    __shared__ float s_bias[128];

    const int tid = threadIdx.x;
    const int b   = blockIdx.y;
    const int l0  = blockIdx.x * 64;

    if (tid < 128) s_bias[tid] = bias[tid];

    for (int idx = tid; idx < 68 * 16; idx += 256) {
        int pos = idx >> 4, co = (idx & 15) * 8;
        int l = l0 - 2 + pos;
        uint4 v = make_uint4(0u, 0u, 0u, 0u);
        if (l >= 0 && l < LIN)
            v = *(const uint4*)&in[((size_t)b * LIN + l) * 128 + co];
        *(uint4*)&s_in[pos * CPL + co] = v;
    }
    __syncthreads();

    const int lane = tid & 63;
    const int mf0  = (tid >> 6) * 2;
    const int lc   = lane & 15;
    const int lk   = (lane >> 4) * 8;

    const f32x4 zero = {0.f, 0.f, 0.f, 0.f};
    f32x4 acc[2][4];
#pragma unroll
    for (int i = 0; i < 2; ++i)
#pragma unroll
        for (int j = 0; j < 4; ++j) acc[i][j] = zero;

    for (int cc = 0; cc < 4; ++cc) {
#pragma unroll
        for (int kk = 0; kk < 5; ++kk) {
            const int step = cc * 5 + kk;
            short8 a[2];
#pragma unroll
            for (int i = 0; i < 2; ++i)
                a[i] = *(const short8*)&Af[(((size_t)step * 8 + mf0 + i) * 64 + lane) * 8];
            short8 bb[4];
#pragma unroll
            for (int j = 0; j < 4; ++j)
                bb[j] = *(const short8*)&s_in[(j * 16 + lc + kk) * CPL + cc * 32 + lk];
#pragma unroll
            for (int i = 0; i < 2; ++i)
#pragma unroll
                for (int j = 0; j < 4; ++j)
                    acc[i][j] = __builtin_amdgcn_mfma_f32_16x16x32_bf16(a[i], bb[j], acc[i][j], 0, 0, 0);
        }
    }

    const int lp0 = l0 >> 1;
#pragma unroll
    for (int i = 0; i < 2; ++i) {
        const int ch0 = (mf0 + i) * 16 + (lane >> 4) * 4;
#pragma unroll
        for (int j = 0; j < 4; ++j) {
            const int n = j * 16 + lc;
            unsigned short pk[4];
#pragma unroll
            for (int r = 0; r < 4; ++r) {
                float v = fmaxf(acc[i][j][r] + s_bias[ch0 + r], 0.f);
                float o = __shfl_xor(v, 1);
                pk[r] = f2bf(fmaxf(v, o));
            }
            if ((lc & 1) == 0)
                *(uint2*)&out[((size_t)b * LOUT + lp0 + (n >> 1)) * 128 + ch0] = *(uint2*)pk;
        }
    }
}

// ---------------------------------------------------------------------------
// conv3 + head, fused. Conv tile 128oc x 64 pre-pool -> pool to 32 pos in LDS,
// then t1=relu(Wo1@f+b), t2=relu(Wo2@t1+b), dot=P@t2, dis, block-min,
// atomicMin into pm (uint bits, positive floats order-preserving).
// ---------------------------------------------------------------------------
__global__ __launch_bounds__(256)
void conv3_head(const unsigned short* __restrict__ in, const unsigned short* __restrict__ Af,
                const float* __restrict__ bias,
                const unsigned short* __restrict__ AW1, const float* __restrict__ bo1,
                const unsigned short* __restrict__ AW2, const float* __restrict__ bo2,
                const unsigned short* __restrict__ AP,  const float* __restrict__ pn,
                unsigned* __restrict__ pm_bits)          // (32,128)
{
    constexpr int LIN = 512, CPL = 136, CP = 136;
    __shared__ __align__(16) unsigned short s_in[68 * CPL];
    __shared__ __align__(16) unsigned short s_f[32 * CP];
    __shared__ float s_bias[128];
    __shared__ float s_part[4 * 32];
    __shared__ float s_fn[32];

    const int tid = threadIdx.x;
    const int b   = blockIdx.y;
    const int l0  = blockIdx.x * 64;

    if (tid < 128) s_bias[tid] = bias[tid];

    for (int idx = tid; idx < 68 * 16; idx += 256) {
        int pos = idx >> 4, co = (idx & 15) * 8;
        int l = l0 - 2 + pos;
        uint4 v = make_uint4(0u, 0u, 0u, 0u);
        if (l >= 0 && l < LIN)
            v = *(const uint4*)&in[((size_t)b * LIN + l) * 128 + co];
        *(uint4*)&s_in[pos * CPL + co] = v;
    }
    __syncthreads();

    const int lane = tid & 63;
    const int mf0  = (tid >> 6) * 2;
    const int lc   = lane & 15;
    const int lk   = (lane >> 4) * 8;

    const f32x4 zero = {0.f, 0.f, 0.f, 0.f};

    // ---- conv3 ----
    f32x4 acc[2][4];
#pragma unroll
    for (int i = 0; i < 2; ++i)
#pragma unroll
        for (int j = 0; j < 4; ++j) acc[i][j] = zero;

    for (int cc = 0; cc < 4; ++cc) {
#pragma unroll
        for (int kk = 0; kk < 5; ++kk) {
            const int step = cc * 5 + kk;
            short8 a[2];
#pragma unroll
            for (int i = 0; i < 2; ++i)
                a[i] = *(const short8*)&Af[(((size_t)step * 8 + mf0 + i) * 64 + lane) * 8];
            short8 bb[4];
#pragma unroll
            for (int j = 0; j < 4; ++j)
                bb[j] = *(const short8*)&s_in[(j * 16 + lc + kk) * CPL + cc * 32 + lk];
#pragma unroll
            for (int i = 0; i < 2; ++i)
#pragma unroll
                for (int j = 0; j < 4; ++j)
                    acc[i][j] = __builtin_amdgcn_mfma_f32_16x16x32_bf16(a[i], bb[j], acc[i][j], 0, 0, 0);
        }
    }

    // pool2 -> s_f[pos 0..31][128]
#pragma unroll
    for (int i = 0; i < 2; ++i) {
        const int ch0 = (mf0 + i) * 16 + (lane >> 4) * 4;
#pragma unroll
        for (int j = 0; j < 4; ++j) {
            const int n = j * 16 + lc;
            unsigned short pk[4];
#pragma unroll
            for (int r = 0; r < 4; ++r) {
                float v = fmaxf(acc[i][j][r] + s_bias[ch0 + r], 0.f);
                float o = __shfl_xor(v, 1);
                pk[r] = f2bf(fmaxf(v, o));
            }
            if ((lc & 1) == 0)
                *(uint2*)&s_f[(n >> 1) * CP + ch0] = *(uint2*)pk;
        }
    }
    __syncthreads();

    // ---- head: N=32 positions, wave covers mf0..mf0+1, hacc[2][2] ----
    f32x4 hacc[2][2];

    auto gemm32 = [&](const unsigned short* __restrict__ A) {
#pragma unroll
        for (int i = 0; i < 2; ++i)
#pragma unroll
            for (int j = 0; j < 2; ++j) hacc[i][j] = zero;
        for (int cc = 0; cc < 4; ++cc) {
            short8 a[2];
#pragma unroll
            for (int i = 0; i < 2; ++i)
                a[i] = *(const short8*)&A[(((size_t)cc * 8 + mf0 + i) * 64 + lane) * 8];
            short8 bb[2];
#pragma unroll
            for (int j = 0; j < 2; ++j)
                bb[j] = *(const short8*)&s_f[(j * 16 + lc) * CP + cc * 32 + lk];
#pragma unroll
            for (int i = 0; i < 2; ++i)
#pragma unroll
                for (int j = 0; j < 2; ++j)
                    hacc[i][j] = __builtin_amdgcn_mfma_f32_16x16x32_bf16(a[i], bb[j], hacc[i][j], 0, 0, 0);
        }
    };

    auto store_relu32 = [&](const float* __restrict__ bv) {
        __syncthreads();   // all reads of s_f done
#pragma unroll
        for (int i = 0; i < 2; ++i) {
            const int ch0 = (mf0 + i) * 16 + (lane >> 4) * 4;
#pragma unroll
            for (int j = 0; j < 2; ++j) {
                const int n = j * 16 + lc;
                unsigned short pk[4];
#pragma unroll
                for (int r = 0; r < 4; ++r)
                    pk[r] = f2bf(fmaxf(hacc[i][j][r] + bv[ch0 + r], 0.f));
                *(uint2*)&s_f[n * CP + ch0] = *(uint2*)pk;
            }
        }
        __syncthreads();
    };

    gemm32(AW1); store_relu32(bo1);
    gemm32(AW2); store_relu32(bo2);

    // fn[n] = ||t2[n]||^2
    if (tid < 128) {
        int n = tid >> 2, part = tid & 3;
        float s = 0.f;
        for (int c = part * 32; c < part * 32 + 32; ++c) {
            float v = bf2f(s_f[n * CP + c]);
            s = fmaf(v, v, s);
        }
        s_part[part * 32 + n] = s;
    }
    __syncthreads();
    if (tid < 32)
        s_fn[tid] = s_part[tid] + s_part[32 + tid] + s_part[64 + tid] + s_part[96 + tid];
    __syncthreads();

    gemm32(AP);

#pragma unroll
    for (int i = 0; i < 2; ++i) {
#pragma unroll
        for (int r = 0; r < 4; ++r) {
            const int p = (mf0 + i) * 16 + (lane >> 4) * 4 + r;
            float m = 3.0e38f;
#pragma unroll
            for (int j = 0; j < 2; ++j) {
                const int n = j * 16 + lc;
                float d2 = s_fn[n] + pn[p] - 2.f * hacc[i][j][r];
                m = fminf(m, sqrtf(fmaxf(d2, 1e-12f)));
            }
#pragma unroll
            for (int s = 1; s < 16; s <<= 1)
                m = fminf(m, __shfl_xor(m, s));
            if (lc == 0)
                atomicMin(&pm_bits[(size_t)b * 128 + p], __float_as_uint(m));
        }
    }
}

// ---------------------------------------------------------------------------
__global__ __launch_bounds__(128)
void finalize_kernel(const float* __restrict__ pm,       // (32,128), already global min
                     const int* __restrict__ classes,
                     float* __restrict__ out)            // [64 sigmoid][4096 min_dis]
{
    __shared__ float r0[128], r1[128];
    const int b = blockIdx.x, p = threadIdx.x;
    float m = pm[(size_t)b * 128 + p];
    out[64 + b * 128 + p] = m;

    float sim = logf((m + 1.0f) / (m + 1e-4f));
    int cls = classes[p];
    r0[p] = (cls == 0) ? sim : -0.5f * sim;
    r1[p] = (cls == 1) ? sim : -0.5f * sim;
    __syncthreads();
    for (int s = 64; s > 0; s >>= 1) {
        if (p < s) { r0[p] += r0[p + s]; r1[p] += r1[p + s]; }
        __syncthreads();
    }
    if (p == 0) {
        out[b * 2 + 0] = 1.f / (1.f + expf(-r0[0]));
        out[b * 2 + 1] = 1.f / (1.f + expf(-r1[0]));
    }
}

// ---------------------------------------------------------------------------
extern "C" void kernel_launch(void* const* d_in, const int* in_sizes, int n_in,
                              void* d_out, int out_size, void* d_ws, size_t ws_size,
                              hipStream_t stream)
{
    (void)in_sizes; (void)n_in; (void)out_size; (void)ws_size;
    const float* x    = (const float*)d_in[0];
    const float* W1   = (const float*)d_in[1];
    const float* b1   = (const float*)d_in[2];
    const float* W2   = (const float*)d_in[3];
    const float* b2   = (const float*)d_in[4];
    const float* W3   = (const float*)d_in[5];
    const float* b3   = (const float*)d_in[6];
    const float* Wo1  = (const float*)d_in[7];
    const float* bo1  = (const float*)d_in[8];
    const float* Wo2  = (const float*)d_in[9];
    const float* bo2  = (const float*)d_in[10];
    const float* prot = (const float*)d_in[11];
    const int*   cls  = (const int*)d_in[12];
    float* out = (float*)d_out;

    // ws layout: h1 (32,1024,128)bf16 8.39M | h2 (32,512,128)bf16 4.19M | frags
    char* ws = (char*)d_ws;
    unsigned short* h1 = (unsigned short*)(ws);
    unsigned short* h2 = (unsigned short*)(ws + 8388608);
    const size_t FR = 12582912;
    unsigned short* A1  = (unsigned short*)(ws + FR);
    unsigned short* A2  = (unsigned short*)(ws + FR + 122880);
    unsigned short* A3  = (unsigned short*)(ws + FR + 286720);
    unsigned short* AW1 = (unsigned short*)(ws + FR + 450560);
    unsigned short* AW2 = (unsigned short*)(ws + FR + 483328);
    unsigned short* AP  = (unsigned short*)(ws + FR + 516096);
    float*          pn  = (float*)(ws + FR + 548864);
    unsigned*       pm  = (unsigned*)(ws + FR + 549376);

    prep_weights_kernel<<<dim3(40, 8), 256, 0, stream>>>(W1, W2, W3, Wo1, Wo2, prot,
                                                         A1, A2, A3, AW1, AW2, AP, pn, pm);
    conv1_mfma<<<dim3(32, 32), 256, 0, stream>>>(x,  A1, b1, h1);
    conv2_mfma<<<dim3(16, 32), 256, 0, stream>>>(h1, A2, b2, h2);
    conv3_head<<<dim3(8, 32), 256, 0, stream>>>(h2, A3, b3, AW1, bo1, AW2, bo2, AP, pn, pm);
    finalize_kernel<<<32, 128, 0, stream>>>((const float*)pm, cls, out);
}

// Round 4
// 130.387 us; speedup vs baseline: 3.0108x; 1.0211x over previous
//
#include <hip/hip_runtime.h>
#include <cmath>

// ProtICU on MI355X — round 4: fused megakernel.
// Per block = (batch b, chunk q of 32 final positions): stage x halo (324 pos)
// -> conv1 (c1 [256q-16,256q+304)) -> h1 in LDS (140 rows)
// -> conv2 (c2 [128q-8,128q+184))  -> h2 in LDS (68 rows, aliases dead x)
// -> conv3 (c3 [64q,64q+64))       -> f  in LDS (32 rows)
// -> head: t1,t2 (1x1 GEMMs), prototype distances, min, atomicMin to global.
// 8 waves/block (4 m-groups x 2 n-groups), v_mfma_f32_16x16x32_bf16, fp32 acc.
// A-fragments pre-packed lane-exact by prep kernel; B from LDS
// (row strides 104/136 shorts -> <=2-way bank alias, free per m136).

typedef __attribute__((ext_vector_type(8))) short short8;
typedef __attribute__((ext_vector_type(4))) float f32x4;

__device__ __forceinline__ unsigned short f2bf(float v) {
    union { float f; unsigned u; } x; x.f = v;
    unsigned r = x.u + 0x7fffu + ((x.u >> 16) & 1u);   // RNE
    return (unsigned short)(r >> 16);
}
__device__ __forceinline__ float bf2f(unsigned short b) {
    union { unsigned u; float f; } x; x.u = ((unsigned)b) << 16;
    return x.f;
}

// ---------------------------------------------------------------------------
// Weight packing into MFMA A-fragment order (16x16x32):
// lane holds A[m = mf*16 + (lane&15)][k = cc*32 + (lane>>4)*8 + j]
// conv: dst[((cc*5+kk)*8+mf)*64+lane][8] = W[m][c][kk]   (c >= C -> 0)
// mat : dst[((cc)*8+mf)*64+lane][8] = M[m][c]
// ---------------------------------------------------------------------------
__device__ void pack_conv_w(int t, int total, const float* __restrict__ W, int C,
                            unsigned short* __restrict__ dst)
{
    if (t >= total) return;
    int lane = t & 63, rest = t >> 6;
    int mf = rest & 7; rest >>= 3;
    int kk = rest % 5, cc = rest / 5;
    int m = mf * 16 + (lane & 15);
    int cb = cc * 32 + (lane >> 4) * 8;
    unsigned short v[8];
#pragma unroll
    for (int j = 0; j < 8; ++j) {
        int c = cb + j;
        v[j] = (c < C) ? f2bf(W[((size_t)m * C + c) * 5 + kk]) : (unsigned short)0;
    }
    *(uint4*)&dst[(size_t)t * 8] = *(uint4*)v;
}

__device__ void pack_mat(int t, const float* __restrict__ M, unsigned short* __restrict__ dst)
{
    if (t >= 2048) return;
    int lane = t & 63, mf = (t >> 6) & 7, cc = t >> 9;
    int m = mf * 16 + (lane & 15);
    int c0 = cc * 32 + (lane >> 4) * 8;
    unsigned short v[8];
#pragma unroll
    for (int j = 0; j < 8; ++j) v[j] = f2bf(M[(size_t)m * 128 + c0 + j]);
    *(uint4*)&dst[(size_t)t * 8] = *(uint4*)v;
}

__global__ __launch_bounds__(256)
void prep_weights_kernel(const float* __restrict__ W1, const float* __restrict__ W2,
                         const float* __restrict__ W3, const float* __restrict__ Wo1,
                         const float* __restrict__ Wo2, const float* __restrict__ protos,
                         unsigned short* A1, unsigned short* A2, unsigned short* A3,
                         unsigned short* AW1, unsigned short* AW2, unsigned short* AP,
                         float* pn, unsigned* pm_bits)
{
    int t = blockIdx.x * 256 + threadIdx.x;
    switch (blockIdx.y) {
    case 0: pack_conv_w(t, 7680,  W1, 76,  A1); break;
    case 1: pack_conv_w(t, 10240, W2, 128, A2); break;
    case 2: pack_conv_w(t, 10240, W3, 128, A3); break;
    case 3: pack_mat(t, Wo1, AW1); break;
    case 4: pack_mat(t, Wo2, AW2); break;
    case 5: pack_mat(t, protos, AP); break;
    case 6:
        if (t < 128) {
            float s = 0.f;
            for (int d = 0; d < 128; ++d) {
                float v = bf2f(f2bf(protos[(size_t)t * 128 + d]));
                s = fmaf(v, v, s);
            }
            pn[t] = s;
        }
        break;
    case 7:
        if (t < 4096) pm_bits[t] = 0x7F800000u;   // +inf init for atomicMin
        break;
    }
}

// ---------------------------------------------------------------------------
// Conv K-loop helper. Wave computes 32 oc (m-frags mf0,mf0+1) x NJ*16 positions.
// row(j,kk) = nbase + j*16 + lc + kk + ROWOFF, optionally clamped to [0,ROWMAX].
// ---------------------------------------------------------------------------
template <int NJ, int NCC, int STRIDE, int ROWOFF, int ROWMAX>
__device__ __forceinline__ void conv_k(const unsigned short* __restrict__ Af,
                                       const unsigned short* __restrict__ sIn,
                                       int nbase, int mf0, int lane,
                                       f32x4 (&acc)[2][NJ])
{
    const int lc = lane & 15;
    const int lk = (lane >> 4) * 8;
#pragma unroll
    for (int i = 0; i < 2; ++i)
#pragma unroll
        for (int j = 0; j < NJ; ++j) acc[i][j] = (f32x4){0.f, 0.f, 0.f, 0.f};

    for (int cc = 0; cc < NCC; ++cc) {
#pragma unroll
        for (int kk = 0; kk < 5; ++kk) {
            const int step = cc * 5 + kk;
            short8 a[2];
#pragma unroll
            for (int i = 0; i < 2; ++i)
                a[i] = *(const short8*)&Af[(((size_t)step * 8 + mf0 + i) * 64 + lane) * 8];
            short8 bb[NJ];
#pragma unroll
            for (int j = 0; j < NJ; ++j) {
                int row = nbase + j * 16 + lc + kk + ROWOFF;
                if (ROWMAX >= 0) row = min(max(row, 0), ROWMAX);
                bb[j] = *(const short8*)&sIn[row * STRIDE + cc * 32 + lk];
            }
#pragma unroll
            for (int j = 0; j < NJ; ++j)
#pragma unroll
                for (int i = 0; i < 2; ++i)
                    acc[i][j] = __builtin_amdgcn_mfma_f32_16x16x32_bf16(a[i], bb[j], acc[i][j], 0, 0, 0);
        }
    }
}

// 1x1 GEMM on 32 positions in s_f (head). acc[2][1] per wave.
__device__ __forceinline__ void gemm_head(const unsigned short* __restrict__ Af,
                                          const unsigned short* __restrict__ s_f,
                                          int nbase, int mf0, int lane,
                                          f32x4 (&acc)[2])
{
    const int lc = lane & 15;
    const int lk = (lane >> 4) * 8;
    acc[0] = (f32x4){0.f, 0.f, 0.f, 0.f};
    acc[1] = (f32x4){0.f, 0.f, 0.f, 0.f};
#pragma unroll
    for (int cc = 0; cc < 4; ++cc) {
        short8 a[2];
#pragma unroll
        for (int i = 0; i < 2; ++i)
            a[i] = *(const short8*)&Af[(((size_t)cc * 8 + mf0 + i) * 64 + lane) * 8];
        short8 bb = *(const short8*)&s_f[(nbase + lc) * 136 + cc * 32 + lk];
#pragma unroll
        for (int i = 0; i < 2; ++i)
            acc[i] = __builtin_amdgcn_mfma_f32_16x16x32_bf16(a[i], bb, acc[i], 0, 0, 0);
    }
}

// ---------------------------------------------------------------------------
// Megakernel: one block per (b, q). 512 threads = 8 waves = 4 m-groups x 2 n-groups.
// ---------------------------------------------------------------------------
__global__ __launch_bounds__(512, 2)
void mega_kernel(const float* __restrict__ x,
                 const unsigned short* __restrict__ A1, const float* __restrict__ b1,
                 const unsigned short* __restrict__ A2, const float* __restrict__ b2,
                 const unsigned short* __restrict__ A3, const float* __restrict__ b3,
                 const unsigned short* __restrict__ AW1, const float* __restrict__ bo1,
                 const unsigned short* __restrict__ AW2, const float* __restrict__ bo2,
                 const unsigned short* __restrict__ AP,  const float* __restrict__ pn,
                 unsigned* __restrict__ pm_bits)
{
    __shared__ __align__(16) unsigned short s_x[324 * 104];   // x tile, bf16 pad96(+8)
    __shared__ __align__(16) unsigned short s_h1[140 * 136];  // h1 rows [128q-6, 128q+134)
    __shared__ float s_cb[768];   // b1|b2|b3|bo1|bo2|pn
    __shared__ float s_part[128];
    __shared__ float s_fn[32];
    unsigned short* s_h2 = s_x;           // 68*136 = 9248 elems (x dead by then)
    unsigned short* s_f  = s_x + 9248;    // 32*136 = 4352 elems

    const int tid  = threadIdx.x;
    const int q    = blockIdx.x;    // 0..7
    const int b    = blockIdx.y;    // 0..31
    const int lane = tid & 63;
    const int wid  = tid >> 6;
    const int mf0  = (wid & 3) * 2;   // m-frags {mf0, mf0+1} => oc [mf0*16, +32)
    const int ng   = wid >> 2;        // n-group 0/1
    const int lc   = lane & 15;
    const int lq   = (lane >> 4) * 4; // acc row quad base

    // ---- stage biases + pn ----
    for (int i = tid; i < 768; i += 512) {
        const float* src = (i < 128) ? b1 : (i < 256) ? b2 : (i < 384) ? b3
                         : (i < 512) ? bo1 : (i < 640) ? bo2 : pn;
        s_cb[i] = src[i & 127];
    }

    // ---- stage x: rows = global l in [256q-18, 256q+306), f32 -> bf16, pad to 96 ----
    const int xbase = 256 * q - 18;
    for (int idx = tid; idx < 324 * 24; idx += 512) {
        int pos = idx / 24, c0 = (idx % 24) * 4;
        int l = xbase + pos;
        unsigned short v[4] = {0, 0, 0, 0};
        if (c0 < 76 && l >= 0 && l < 2048) {
            float4 xv = *(const float4*)&x[((size_t)b * 2048 + l) * 76 + c0];
            v[0] = f2bf(xv.x); v[1] = f2bf(xv.y); v[2] = f2bf(xv.z); v[3] = f2bf(xv.w);
        }
        *(uint2*)&s_x[pos * 104 + c0] = *(uint2*)v;
    }
    __syncthreads();

    // ================= conv1: c1 [256q-16, 256q+304), NJ=10 =================
    {
        f32x4 acc[2][10];
        conv_k<10, 3, 104, 0, -1>(A1, s_x, ng * 160, mf0, lane, acc);

        // bias+relu+pool2 -> s_h1 (row jh = (nl>>1)-2, global j = 128q-6+jh)
#pragma unroll
        for (int i = 0; i < 2; ++i) {
            const int ch0 = (mf0 + i) * 16 + lq;
#pragma unroll
            for (int j = 0; j < 10; ++j) {
                const int nl = ng * 160 + j * 16 + lc;
                unsigned short pk[4];
#pragma unroll
                for (int r = 0; r < 4; ++r) {
                    float v = fmaxf(acc[i][j][r] + s_cb[ch0 + r], 0.f);
                    float o = __shfl_xor(v, 1);
                    pk[r] = f2bf(fmaxf(v, o));
                }
                if ((lc & 1) == 0) {
                    int jh = (nl >> 1) - 2;
                    int jg = 128 * q - 6 + jh;
                    if (jh >= 0 && jh < 140) {
                        uint2 val = (jg >= 0 && jg < 1024) ? *(uint2*)pk : make_uint2(0u, 0u);
                        *(uint2*)&s_h1[jh * 136 + ch0] = val;
                    }
                }
            }
        }
    }
    __syncthreads();   // h1 complete; s_x dead -> s_h2/s_f regions reusable

    // ================= conv2: c2 [128q-8, 128q+184), NJ=6, rows clamped ======
    {
        f32x4 acc[2][6];
        conv_k<6, 4, 136, -4, 139>(A2, s_h1, ng * 96, mf0, lane, acc);

#pragma unroll
        for (int i = 0; i < 2; ++i) {
            const int ch0 = (mf0 + i) * 16 + lq;
#pragma unroll
            for (int j = 0; j < 6; ++j) {
                const int nl = ng * 96 + j * 16 + lc;
                unsigned short pk[4];
#pragma unroll
                for (int r = 0; r < 4; ++r) {
                    float v = fmaxf(acc[i][j][r] + s_cb[128 + ch0 + r], 0.f);
                    float o = __shfl_xor(v, 1);
                    pk[r] = f2bf(fmaxf(v, o));
                }
                if ((lc & 1) == 0) {
                    int jh = (nl >> 1) - 2;
                    int jg = 64 * q - 2 + jh;
                    if (jh >= 0 && jh < 68) {
                        uint2 val = (jg >= 0 && jg < 512) ? *(uint2*)pk : make_uint2(0u, 0u);
                        *(uint2*)&s_h2[jh * 136 + ch0] = val;
                    }
                }
            }
        }
    }
    __syncthreads();   // h2 complete

    // ================= conv3: c3 [64q, 64q+64), NJ=2, exact rows =============
    {
        f32x4 acc[2][2];
        conv_k<2, 4, 136, 0, -1>(A3, s_h2, ng * 32, mf0, lane, acc);

#pragma unroll
        for (int i = 0; i < 2; ++i) {
            const int ch0 = (mf0 + i) * 16 + lq;
#pragma unroll
            for (int j = 0; j < 2; ++j) {
                const int nl = ng * 32 + j * 16 + lc;
                unsigned short pk[4];
#pragma unroll
                for (int r = 0; r < 4; ++r) {
                    float v = fmaxf(acc[i][j][r] + s_cb[256 + ch0 + r], 0.f);
                    float o = __shfl_xor(v, 1);
                    pk[r] = f2bf(fmaxf(v, o));
                }
                if ((lc & 1) == 0)
                    *(uint2*)&s_f[(nl >> 1) * 136 + ch0] = *(uint2*)pk;
            }
        }
    }
    __syncthreads();   // f complete (32 positions x 128 ch)

    // ================= head =================
    f32x4 hacc[2];

    // t1 = relu(Wo1 @ f + bo1)
    gemm_head(AW1, s_f, ng * 16, mf0, lane, hacc);
    __syncthreads();
#pragma unroll
    for (int i = 0; i < 2; ++i) {
        const int ch0 = (mf0 + i) * 16 + lq;
        unsigned short pk[4];
#pragma unroll
        for (int r = 0; r < 4; ++r)
            pk[r] = f2bf(fmaxf(hacc[i][r] + s_cb[384 + ch0 + r], 0.f));
        *(uint2*)&s_f[(ng * 16 + lc) * 136 + ch0] = *(uint2*)pk;
    }
    __syncthreads();

    // t2 = relu(Wo2 @ t1 + bo2)
    gemm_head(AW2, s_f, ng * 16, mf0, lane, hacc);
    __syncthreads();
#pragma unroll
    for (int i = 0; i < 2; ++i) {
        const int ch0 = (mf0 + i) * 16 + lq;
        unsigned short pk[4];
#pragma unroll
        for (int r = 0; r < 4; ++r)
            pk[r] = f2bf(fmaxf(hacc[i][r] + s_cb[512 + ch0 + r], 0.f));
        *(uint2*)&s_f[(ng * 16 + lc) * 136 + ch0] = *(uint2*)pk;
    }
    __syncthreads();

    // fn[n] = ||t2[n]||^2
    if (tid < 128) {
        int n = tid >> 2, part = tid & 3;
        float s = 0.f;
        for (int c = part * 32; c < part * 32 + 32; ++c) {
            float v = bf2f(s_f[n * 136 + c]);
            s = fmaf(v, v, s);
        }
        s_part[part * 32 + n] = s;
    }
    __syncthreads();
    if (tid < 32)
        s_fn[tid] = s_part[tid] + s_part[32 + tid] + s_part[64 + tid] + s_part[96 + tid];
    __syncthreads();

    // dot = P @ t2 ; dis = sqrt(fn + pn - 2 dot) ; min over 32 positions
    gemm_head(AP, s_f, ng * 16, mf0, lane, hacc);
#pragma unroll
    for (int i = 0; i < 2; ++i) {
#pragma unroll
        for (int r = 0; r < 4; ++r) {
            const int p = (mf0 + i) * 16 + lq + r;
            const int n = ng * 16 + lc;
            float d2 = s_fn[n] + s_cb[640 + p] - 2.f * hacc[i][r];
            float m = sqrtf(fmaxf(d2, 1e-12f));
#pragma unroll
            for (int s = 1; s < 16; s <<= 1)
                m = fminf(m, __shfl_xor(m, s));
            if (lc == 0)
                atomicMin(&pm_bits[(size_t)b * 128 + p], __float_as_uint(m));
        }
    }
}

// ---------------------------------------------------------------------------
__global__ __launch_bounds__(128)
void finalize_kernel(const float* __restrict__ pm,       // (32,128) global min
                     const int* __restrict__ classes,
                     float* __restrict__ out)            // [64 sigmoid][4096 min_dis]
{
    __shared__ float r0[128], r1[128];
    const int b = blockIdx.x, p = threadIdx.x;
    float m = pm[(size_t)b * 128 + p];
    out[64 + b * 128 + p] = m;

    float sim = logf((m + 1.0f) / (m + 1e-4f));
    int cls = classes[p];
    r0[p] = (cls == 0) ? sim : -0.5f * sim;
    r1[p] = (cls == 1) ? sim : -0.5f * sim;
    __syncthreads();
    for (int s = 64; s > 0; s >>= 1) {
        if (p < s) { r0[p] += r0[p + s]; r1[p] += r1[p + s]; }
        __syncthreads();
    }
    if (p == 0) {
        out[b * 2 + 0] = 1.f / (1.f + expf(-r0[0]));
        out[b * 2 + 1] = 1.f / (1.f + expf(-r1[0]));
    }
}

// ---------------------------------------------------------------------------
extern "C" void kernel_launch(void* const* d_in, const int* in_sizes, int n_in,
                              void* d_out, int out_size, void* d_ws, size_t ws_size,
                              hipStream_t stream)
{
    (void)in_sizes; (void)n_in; (void)out_size; (void)ws_size;
    const float* x    = (const float*)d_in[0];
    const float* W1   = (const float*)d_in[1];
    const float* b1   = (const float*)d_in[2];
    const float* W2   = (const float*)d_in[3];
    const float* b2   = (const float*)d_in[4];
    const float* W3   = (const float*)d_in[5];
    const float* b3   = (const float*)d_in[6];
    const float* Wo1  = (const float*)d_in[7];
    const float* bo1  = (const float*)d_in[8];
    const float* Wo2  = (const float*)d_in[9];
    const float* bo2  = (const float*)d_in[10];
    const float* prot = (const float*)d_in[11];
    const int*   cls  = (const int*)d_in[12];
    float* out = (float*)d_out;

    // ws: A-fragments + pn + pm only (~566 KB)
    char* ws = (char*)d_ws;
    unsigned short* A1  = (unsigned short*)(ws);
    unsigned short* A2  = (unsigned short*)(ws + 122880);
    unsigned short* A3  = (unsigned short*)(ws + 286720);
    unsigned short* AW1 = (unsigned short*)(ws + 450560);
    unsigned short* AW2 = (unsigned short*)(ws + 483328);
    unsigned short* AP  = (unsigned short*)(ws + 516096);
    float*          pn  = (float*)(ws + 548864);
    unsigned*       pm  = (unsigned*)(ws + 549376);

    prep_weights_kernel<<<dim3(40, 8), 256, 0, stream>>>(W1, W2, W3, Wo1, Wo2, prot,
                                                         A1, A2, A3, AW1, AW2, AP, pn, pm);
    mega_kernel<<<dim3(8, 32), 512, 0, stream>>>(x, A1, b1, A2, b2, A3, b3,
                                                 AW1, bo1, AW2, bo2, AP, pn, pm);
    finalize_kernel<<<32, 128, 0, stream>>>((const float*)pm, cls, out);
}

// Round 5
// 130.198 us; speedup vs baseline: 3.0151x; 1.0015x over previous
//
#include <hip/hip_runtime.h>
#include <cmath>

// ProtICU on MI355X — round 5: fused megakernel, 512 blocks x 4 waves.
// Block = (batch b, chunk u of 16 final positions). 4 waves = 2 mgroups x 2 ngroups;
// each wave owns 4 m-frags (64 oc) -> every LDS B-fragment feeds 4 MFMAs (was 2).
// LDS ~67 KB -> 2 blocks/CU (inter-block overlap hides barriers/staging).
// Pipeline per block: stage x halo (196 rows, f32->bf16) -> conv1 -> h1 (84 rows LDS)
// -> conv2 -> h2 (40 rows, aliases dead x) -> conv3 -> f (16 rows) -> head GEMMs
// -> prototype distances -> lane-min -> global atomicMin.
// All GEMMs v_mfma_f32_16x16x32_bf16, fp32 acc. A-frags pre-packed lane-exact in ws.

typedef __attribute__((ext_vector_type(8))) short short8;
typedef __attribute__((ext_vector_type(4))) float f32x4;

__device__ __forceinline__ unsigned short f2bf(float v) {
    union { float f; unsigned u; } x; x.f = v;
    unsigned r = x.u + 0x7fffu + ((x.u >> 16) & 1u);   // RNE
    return (unsigned short)(r >> 16);
}
__device__ __forceinline__ float bf2f(unsigned short b) {
    union { unsigned u; float f; } x; x.u = ((unsigned)b) << 16;
    return x.f;
}

// ---------------------------------------------------------------------------
// Weight packing into MFMA A-fragment order (16x16x32):
// lane holds A[m = mf*16 + (lane&15)][k = cc*32 + (lane>>4)*8 + j]
// conv: dst[((cc*5+kk)*8+mf)*64+lane][8] = W[m][c][kk]   (c >= C -> 0)
// mat : dst[((cc)*8+mf)*64+lane][8] = M[m][c]
// ---------------------------------------------------------------------------
__device__ void pack_conv_w(int t, int total, const float* __restrict__ W, int C,
                            unsigned short* __restrict__ dst)
{
    if (t >= total) return;
    int lane = t & 63, rest = t >> 6;
    int mf = rest & 7; rest >>= 3;
    int kk = rest % 5, cc = rest / 5;
    int m = mf * 16 + (lane & 15);
    int cb = cc * 32 + (lane >> 4) * 8;
    unsigned short v[8];
#pragma unroll
    for (int j = 0; j < 8; ++j) {
        int c = cb + j;
        v[j] = (c < C) ? f2bf(W[((size_t)m * C + c) * 5 + kk]) : (unsigned short)0;
    }
    *(uint4*)&dst[(size_t)t * 8] = *(uint4*)v;
}

__device__ void pack_mat(int t, const float* __restrict__ M, unsigned short* __restrict__ dst)
{
    if (t >= 2048) return;
    int lane = t & 63, mf = (t >> 6) & 7, cc = t >> 9;
    int m = mf * 16 + (lane & 15);
    int c0 = cc * 32 + (lane >> 4) * 8;
    unsigned short v[8];
#pragma unroll
    for (int j = 0; j < 8; ++j) v[j] = f2bf(M[(size_t)m * 128 + c0 + j]);
    *(uint4*)&dst[(size_t)t * 8] = *(uint4*)v;
}

__global__ __launch_bounds__(256)
void prep_weights_kernel(const float* __restrict__ W1, const float* __restrict__ W2,
                         const float* __restrict__ W3, const float* __restrict__ Wo1,
                         const float* __restrict__ Wo2, const float* __restrict__ protos,
                         unsigned short* A1, unsigned short* A2, unsigned short* A3,
                         unsigned short* AW1, unsigned short* AW2, unsigned short* AP,
                         float* pn, unsigned* pm_bits)
{
    int t = blockIdx.x * 256 + threadIdx.x;
    switch (blockIdx.y) {
    case 0: pack_conv_w(t, 7680,  W1, 76,  A1); break;
    case 1: pack_conv_w(t, 10240, W2, 128, A2); break;
    case 2: pack_conv_w(t, 10240, W3, 128, A3); break;
    case 3: pack_mat(t, Wo1, AW1); break;
    case 4: pack_mat(t, Wo2, AW2); break;
    case 5: pack_mat(t, protos, AP); break;
    case 6:
        if (t < 128) {
            float s = 0.f;
            for (int d = 0; d < 128; ++d) {
                float v = bf2f(f2bf(protos[(size_t)t * 128 + d]));
                s = fmaf(v, v, s);
            }
            pn[t] = s;
        }
        break;
    case 7:
        if (t < 4096) pm_bits[t] = 0x7F800000u;   // +inf init for atomicMin
        break;
    }
}

// ---------------------------------------------------------------------------
// Conv K-loop: wave computes 4 m-frags (mf0..mf0+3) x NJ*16 rows at nbase.
// B row (local) = nbase + j*16 + lc + kk, clamped to ROWMAX if >=0.
// ---------------------------------------------------------------------------
template <int NJ, int NCC, int STRIDE, int ROWMAX>
__device__ __forceinline__ void conv_k(const unsigned short* __restrict__ Af,
                                       const unsigned short* __restrict__ sIn,
                                       int nbase, int mf0, int lane,
                                       f32x4 (&acc)[4][NJ])
{
    const int lc = lane & 15;
    const int lk = (lane >> 4) * 8;
#pragma unroll
    for (int i = 0; i < 4; ++i)
#pragma unroll
        for (int j = 0; j < NJ; ++j) acc[i][j] = (f32x4){0.f, 0.f, 0.f, 0.f};

    for (int cc = 0; cc < NCC; ++cc) {
#pragma unroll
        for (int kk = 0; kk < 5; ++kk) {
            const int step = cc * 5 + kk;
            short8 a[4];
#pragma unroll
            for (int i = 0; i < 4; ++i)
                a[i] = *(const short8*)&Af[(((size_t)step * 8 + mf0 + i) * 64 + lane) * 8];
            short8 bb[NJ];
#pragma unroll
            for (int j = 0; j < NJ; ++j) {
                int row = nbase + j * 16 + lc + kk;
                if (ROWMAX >= 0) row = min(row, ROWMAX);
                bb[j] = *(const short8*)&sIn[row * STRIDE + cc * 32 + lk];
            }
#pragma unroll
            for (int j = 0; j < NJ; ++j)
#pragma unroll
                for (int i = 0; i < 4; ++i)
                    acc[i][j] = __builtin_amdgcn_mfma_f32_16x16x32_bf16(a[i], bb[j], acc[i][j], 0, 0, 0);
        }
    }
}

// 1x1 GEMM over the 16 head positions; wave owns 2 m-frags (mf0h, mf0h+1).
__device__ __forceinline__ void gemm_head(const unsigned short* __restrict__ Af,
                                          const unsigned short* __restrict__ s_f,
                                          int mf0h, int lane, f32x4 (&acc)[2])
{
    const int lc = lane & 15;
    const int lk = (lane >> 4) * 8;
    acc[0] = (f32x4){0.f, 0.f, 0.f, 0.f};
    acc[1] = (f32x4){0.f, 0.f, 0.f, 0.f};
#pragma unroll
    for (int cc = 0; cc < 4; ++cc) {
        short8 a[2];
#pragma unroll
        for (int i = 0; i < 2; ++i)
            a[i] = *(const short8*)&Af[(((size_t)cc * 8 + mf0h + i) * 64 + lane) * 8];
        short8 bb = *(const short8*)&s_f[lc * 136 + cc * 32 + lk];
#pragma unroll
        for (int i = 0; i < 2; ++i)
            acc[i] = __builtin_amdgcn_mfma_f32_16x16x32_bf16(a[i], bb, acc[i], 0, 0, 0);
    }
}

// ---------------------------------------------------------------------------
// Megakernel: block = (u, b), 256 threads = 4 waves = 2 mg x 2 ng.
// ---------------------------------------------------------------------------
__global__ __launch_bounds__(256, 2)
void mega_kernel(const float* __restrict__ x,
                 const unsigned short* __restrict__ A1, const float* __restrict__ b1,
                 const unsigned short* __restrict__ A2, const float* __restrict__ b2,
                 const unsigned short* __restrict__ A3, const float* __restrict__ b3,
                 const unsigned short* __restrict__ AW1, const float* __restrict__ bo1,
                 const unsigned short* __restrict__ AW2, const float* __restrict__ bo2,
                 const unsigned short* __restrict__ AP,  const float* __restrict__ pn,
                 unsigned* __restrict__ pm_bits)
{
    __shared__ __align__(16) unsigned short s_x[196 * 104];  // x rows [128u-14, 128u+182)
    __shared__ __align__(16) unsigned short s_h1[84 * 136];  // h1 rows [64u-6, 64u+78)
    __shared__ float s_cb[768];      // b1|b2|b3|bo1|bo2|pn
    __shared__ float s_part[64];
    __shared__ float s_fn[16];
    unsigned short* s_h2 = s_x;          // 40*136 = 5440 shorts (x dead after conv1)
    unsigned short* s_f  = s_x + 5440;   // 16*136 = 2176 shorts

    const int tid  = threadIdx.x;
    const int u    = blockIdx.x;    // 0..15
    const int b    = blockIdx.y;    // 0..31
    const int lane = tid & 63;
    const int wid  = tid >> 6;      // 0..3
    const int mg   = wid & 1;       // m-group: frags 4mg..4mg+3 (oc 64mg..64mg+63)
    const int ng   = wid >> 1;      // n-group 0/1
    const int mf0  = mg * 4;
    const int lc   = lane & 15;
    const int lq   = (lane >> 4) * 4;

    // ---- stage biases + pn ----
    for (int i = tid; i < 768; i += 256) {
        const float* src = (i < 128) ? b1 : (i < 256) ? b2 : (i < 384) ? b3
                         : (i < 512) ? bo1 : (i < 640) ? bo2 : pn;
        s_cb[i] = src[i & 127];
    }

    // ---- stage x: rows l in [128u-14, 128u+182), f32 -> bf16, pad 76 -> 96 ch ----
    const int xbase = 128 * u - 14;
    for (int idx = tid; idx < 196 * 24; idx += 256) {
        int pos = idx / 24, c0 = (idx % 24) * 4;
        int l = xbase + pos;
        unsigned short v[4] = {0, 0, 0, 0};
        if (c0 < 76 && l >= 0 && l < 2048) {
            float4 xv = *(const float4*)&x[((size_t)b * 2048 + l) * 76 + c0];
            v[0] = f2bf(xv.x); v[1] = f2bf(xv.y); v[2] = f2bf(xv.z); v[3] = f2bf(xv.w);
        }
        *(uint2*)&s_x[pos * 104 + c0] = *(uint2*)v;
    }
    __syncthreads();

    // ============ conv1: c1 rows [128u-12, 128u+180), NJ=6 per ng ============
    {
        f32x4 acc[4][6];
        conv_k<6, 3, 104, -1>(A1, s_x, ng * 96, mf0, lane, acc);

        // bias+relu+pool2 -> s_h1 local r = nl/2 (global jg = 64u-6+r), keep r<84
#pragma unroll
        for (int i = 0; i < 4; ++i) {
            const int ch0 = (mf0 + i) * 16 + lq;
#pragma unroll
            for (int j = 0; j < 6; ++j) {
                const int nl = ng * 96 + j * 16 + lc;
                unsigned short pk[4];
#pragma unroll
                for (int r = 0; r < 4; ++r) {
                    float v = fmaxf(acc[i][j][r] + s_cb[ch0 + r], 0.f);
                    float o = __shfl_xor(v, 1);
                    pk[r] = f2bf(fmaxf(v, o));
                }
                if ((lc & 1) == 0) {
                    int rr = nl >> 1;
                    int jg = 64 * u - 6 + rr;
                    if (rr < 84) {
                        uint2 val = (jg >= 0 && jg < 1024) ? *(uint2*)pk : make_uint2(0u, 0u);
                        *(uint2*)&s_h1[rr * 136 + ch0] = val;
                    }
                }
            }
        }
    }
    __syncthreads();   // h1 complete; s_x dead -> s_h2/s_f reusable

    // ============ conv2: c2 rows [64u-4, 64u+92), NJ=3 per ng, clamp r<=83 ====
    {
        f32x4 acc[4][3];
        conv_k<3, 4, 136, 83>(A2, s_h1, ng * 48, mf0, lane, acc);

#pragma unroll
        for (int i = 0; i < 4; ++i) {
            const int ch0 = (mf0 + i) * 16 + lq;
#pragma unroll
            for (int j = 0; j < 3; ++j) {
                const int nl = ng * 48 + j * 16 + lc;
                unsigned short pk[4];
#pragma unroll
                for (int r = 0; r < 4; ++r) {
                    float v = fmaxf(acc[i][j][r] + s_cb[128 + ch0 + r], 0.f);
                    float o = __shfl_xor(v, 1);
                    pk[r] = f2bf(fmaxf(v, o));
                }
                if ((lc & 1) == 0) {
                    int rr = nl >> 1;             // h2 local, global jg = 32u-2+rr
                    int jg = 32 * u - 2 + rr;
                    if (rr < 40) {
                        uint2 val = (jg >= 0 && jg < 512) ? *(uint2*)pk : make_uint2(0u, 0u);
                        *(uint2*)&s_h2[rr * 136 + ch0] = val;
                    }
                }
            }
        }
    }
    __syncthreads();   // h2 complete

    // ============ conv3: c3 rows [32u, 32u+32), NJ=1 per ng ===================
    {
        f32x4 acc[4][1];
        conv_k<1, 4, 136, -1>(A3, s_h2, ng * 16, mf0, lane, acc);

#pragma unroll
        for (int i = 0; i < 4; ++i) {
            const int ch0 = (mf0 + i) * 16 + lq;
            const int nl = ng * 16 + lc;
            unsigned short pk[4];
#pragma unroll
            for (int r = 0; r < 4; ++r) {
                float v = fmaxf(acc[i][0][r] + s_cb[256 + ch0 + r], 0.f);
                float o = __shfl_xor(v, 1);
                pk[r] = f2bf(fmaxf(v, o));
            }
            if ((lc & 1) == 0)
                *(uint2*)&s_f[(nl >> 1) * 136 + ch0] = *(uint2*)pk;
        }
    }
    __syncthreads();   // f complete (16 positions x 128 ch)

    // ============ head: wave owns m-frags {2wid, 2wid+1} ======================
    const int mf0h = wid * 2;
    f32x4 hacc[2];

    gemm_head(AW1, s_f, mf0h, lane, hacc);     // t1 = relu(Wo1 f + bo1)
    __syncthreads();
#pragma unroll
    for (int i = 0; i < 2; ++i) {
        const int ch0 = (mf0h + i) * 16 + lq;
        unsigned short pk[4];
#pragma unroll
        for (int r = 0; r < 4; ++r)
            pk[r] = f2bf(fmaxf(hacc[i][r] + s_cb[384 + ch0 + r], 0.f));
        *(uint2*)&s_f[lc * 136 + ch0] = *(uint2*)pk;
    }
    __syncthreads();

    gemm_head(AW2, s_f, mf0h, lane, hacc);     // t2 = relu(Wo2 t1 + bo2)
    __syncthreads();
#pragma unroll
    for (int i = 0; i < 2; ++i) {
        const int ch0 = (mf0h + i) * 16 + lq;
        unsigned short pk[4];
#pragma unroll
        for (int r = 0; r < 4; ++r)
            pk[r] = f2bf(fmaxf(hacc[i][r] + s_cb[512 + ch0 + r], 0.f));
        *(uint2*)&s_f[lc * 136 + ch0] = *(uint2*)pk;
    }
    __syncthreads();

    // fn[n] = ||t2[n]||^2, n in [0,16)
    if (tid < 64) {
        int n = tid >> 2, part = tid & 3;
        float s = 0.f;
        for (int c = part * 32; c < part * 32 + 32; ++c) {
            float v = bf2f(s_f[n * 136 + c]);
            s = fmaf(v, v, s);
        }
        s_part[part * 16 + n] = s;
    }
    __syncthreads();
    if (tid < 16)
        s_fn[tid] = s_part[tid] + s_part[16 + tid] + s_part[32 + tid] + s_part[48 + tid];
    __syncthreads();

    gemm_head(AP, s_f, mf0h, lane, hacc);      // dot = P t2

#pragma unroll
    for (int i = 0; i < 2; ++i) {
#pragma unroll
        for (int r = 0; r < 4; ++r) {
            const int p = (mf0h + i) * 16 + lq + r;
            float d2 = s_fn[lc] + s_cb[640 + p] - 2.f * hacc[i][r];
            float m = sqrtf(fmaxf(d2, 1e-12f));
#pragma unroll
            for (int s = 1; s < 16; s <<= 1)
                m = fminf(m, __shfl_xor(m, s));
            if (lc == 0)
                atomicMin(&pm_bits[(size_t)b * 128 + p], __float_as_uint(m));
        }
    }
}

// ---------------------------------------------------------------------------
__global__ __launch_bounds__(128)
void finalize_kernel(const float* __restrict__ pm,       // (32,128) global min
                     const int* __restrict__ classes,
                     float* __restrict__ out)            // [64 sigmoid][4096 min_dis]
{
    __shared__ float r0[128], r1[128];
    const int b = blockIdx.x, p = threadIdx.x;
    float m = pm[(size_t)b * 128 + p];
    out[64 + b * 128 + p] = m;

    float sim = logf((m + 1.0f) / (m + 1e-4f));
    int cls = classes[p];
    r0[p] = (cls == 0) ? sim : -0.5f * sim;
    r1[p] = (cls == 1) ? sim : -0.5f * sim;
    __syncthreads();
    for (int s = 64; s > 0; s >>= 1) {
        if (p < s) { r0[p] += r0[p + s]; r1[p] += r1[p + s]; }
        __syncthreads();
    }
    if (p == 0) {
        out[b * 2 + 0] = 1.f / (1.f + expf(-r0[0]));
        out[b * 2 + 1] = 1.f / (1.f + expf(-r1[0]));
    }
}

// ---------------------------------------------------------------------------
extern "C" void kernel_launch(void* const* d_in, const int* in_sizes, int n_in,
                              void* d_out, int out_size, void* d_ws, size_t ws_size,
                              hipStream_t stream)
{
    (void)in_sizes; (void)n_in; (void)out_size; (void)ws_size;
    const float* x    = (const float*)d_in[0];
    const float* W1   = (const float*)d_in[1];
    const float* b1   = (const float*)d_in[2];
    const float* W2   = (const float*)d_in[3];
    const float* b2   = (const float*)d_in[4];
    const float* W3   = (const float*)d_in[5];
    const float* b3   = (const float*)d_in[6];
    const float* Wo1  = (const float*)d_in[7];
    const float* bo1  = (const float*)d_in[8];
    const float* Wo2  = (const float*)d_in[9];
    const float* bo2  = (const float*)d_in[10];
    const float* prot = (const float*)d_in[11];
    const int*   cls  = (const int*)d_in[12];
    float* out = (float*)d_out;

    // ws: A-fragments + pn + pm only (~566 KB)
    char* ws = (char*)d_ws;
    unsigned short* A1  = (unsigned short*)(ws);
    unsigned short* A2  = (unsigned short*)(ws + 122880);
    unsigned short* A3  = (unsigned short*)(ws + 286720);
    unsigned short* AW1 = (unsigned short*)(ws + 450560);
    unsigned short* AW2 = (unsigned short*)(ws + 483328);
    unsigned short* AP  = (unsigned short*)(ws + 516096);
    float*          pn  = (float*)(ws + 548864);
    unsigned*       pm  = (unsigned*)(ws + 549376);

    prep_weights_kernel<<<dim3(40, 8), 256, 0, stream>>>(W1, W2, W3, Wo1, Wo2, prot,
                                                         A1, A2, A3, AW1, AW2, AP, pn, pm);
    mega_kernel<<<dim3(16, 32), 256, 0, stream>>>(x, A1, b1, A2, b2, A3, b3,
                                                  AW1, bo1, AW2, bo2, AP, pn, pm);
    finalize_kernel<<<32, 128, 0, stream>>>((const float*)pm, cls, out);
}